// Round 1
// 468.523 us; speedup vs baseline: 1.0516x; 1.0516x over previous
//
#include <hip/hip_runtime.h>

#define NS_ 100000
#define NW_ 400000
#define NE_ 500000
#define EPB 2048   // elements per scan block

typedef float f32x4_t __attribute__((ext_vector_type(4)));
typedef unsigned u32x4_t __attribute__((ext_vector_type(4)));

__device__ __forceinline__ float lrelu02(float x) { return x > 0.f ? x : 0.2f * x; }
__device__ __forceinline__ float bf2f(unsigned short u) {
    return __uint_as_float(((unsigned)u) << 16);
}
__device__ __forceinline__ unsigned short f2bf(float f) {
    unsigned u = __float_as_uint(f);
    u += 0x7FFFu + ((u >> 16) & 1u);           // round-to-nearest-even
    return (unsigned short)(u >> 16);
}
__device__ __forceinline__ unsigned pk(float lo, float hi) {
    return (unsigned)f2bf(lo) | ((unsigned)f2bf(hi) << 16);
}
// D = A*B + D, 16x16x32 bf16. a/b = 8 bf16 packed in 4 dwords (k ascending).
// A[m=lane&15][k=(lane>>4)*8+j]; B[k=(lane>>4)*8+j][n=lane&15];
// D: col=lane&15, row=(lane>>4)*4+reg.   (layout HW-verified in rounds 4/5)
__device__ __forceinline__ void mfma_bf16(f32x4_t& acc, u32x4_t a, u32x4_t b) {
    asm volatile("v_mfma_f32_16x16x32_bf16 %0, %1, %2, %0" : "+v"(acc) : "v"(a), "v"(b));
}

// ---------------------------------------------------------------------------
// Prep (single block): vd/vs attention vectors + all weight B-fragments.
// fw : 8 frags  : Wc = Wl_ww + Wr_ww                      (wells dense, K=64)
// fs : 16 frags : kc0-1 Wl_ws (mn), kc2-3 Wr_ws+mean W_ss (sites dense, K=128)
// fsp: 32 frags : W_sw [64,256] for the sites projection   (kc*16+ct)
// ---------------------------------------------------------------------------
__global__ void __launch_bounds__(256)
k_prep(const float* __restrict__ W_sw, const float* __restrict__ att_src,
       const float* __restrict__ att_dst,
       const float* __restrict__ Wl_ww, const float* __restrict__ Wr_ww,
       const float* __restrict__ Wl_ws, const float* __restrict__ Wr_ws,
       const float* __restrict__ W_ss,
       float* __restrict__ vd, float* __restrict__ vs,
       u32x4_t* __restrict__ fw, u32x4_t* __restrict__ fs,
       u32x4_t* __restrict__ fsp)
{
    const int tid = threadIdx.x;
    {   // vd (att_dst) and vs (att_src): v[d*4+h] = sum_c W_sw[d,h*64+c]*att[h,c]
        int d = tid >> 2, h = tid & 3;
        const float4* wp = (const float4*)(W_sw + d * 256 + h * 64);
        const float4* ad = (const float4*)(att_dst + h * 64);
        const float4* as = (const float4*)(att_src + h * 64);
        float accd = 0.f, accs = 0.f;
#pragma unroll
        for (int c = 0; c < 16; ++c) {
            float4 wv = wp[c]; float4 dv = ad[c]; float4 sv = as[c];
            accd += wv.x * dv.x + wv.y * dv.y + wv.z * dv.z + wv.w * dv.w;
            accs += wv.x * sv.x + wv.y * sv.y + wv.z * sv.z + wv.w * sv.w;
        }
        vd[d * 4 + h] = accd;
        vs[d * 4 + h] = accs;
    }
    for (int idx = tid; idx < 512; idx += 256) {
        int f = idx >> 6, lane = idx & 63;
        int kc = f >> 2, ct = f & 3, q = lane >> 4, n = lane & 15;
        int c = ct * 16 + n;
        u32x4_t d;
#pragma unroll
        for (int i = 0; i < 4; ++i) {
            int k = kc * 32 + q * 8 + 2 * i;
            d[i] = pk(Wl_ww[k * 64 + c] + Wr_ww[k * 64 + c],
                      Wl_ww[(k + 1) * 64 + c] + Wr_ww[(k + 1) * 64 + c]);
        }
        fw[idx] = d;
    }
    for (int idx = tid; idx < 1024; idx += 256) {
        int f = idx >> 6, lane = idx & 63;
        int kc = f >> 2, ct = f & 3, q = lane >> 4, n = lane & 15;
        int c = ct * 16 + n;
        u32x4_t d;
#pragma unroll
        for (int i = 0; i < 4; ++i) {
            int k = kc * 32 + q * 8 + 2 * i;
            float lo, hi;
            if (k < 64) {
                lo = Wl_ws[k * 64 + c];
                hi = Wl_ws[(k + 1) * 64 + c];
            } else {
                int kk = k - 64;
                lo = Wr_ws[kk * 64 + c] + 0.25f * (W_ss[kk * 256 + c] + W_ss[kk * 256 + 64 + c] +
                                                   W_ss[kk * 256 + 128 + c] + W_ss[kk * 256 + 192 + c]);
                hi = Wr_ws[(kk + 1) * 64 + c] + 0.25f * (W_ss[(kk + 1) * 256 + c] + W_ss[(kk + 1) * 256 + 64 + c] +
                                                         W_ss[(kk + 1) * 256 + 128 + c] + W_ss[(kk + 1) * 256 + 192 + c]);
            }
            d[i] = pk(lo, hi);
        }
        fs[idx] = d;
    }
    for (int idx = tid; idx < 2048; idx += 256) {
        int f = idx >> 6, lane = idx & 63;
        int kc = f >> 4, ct = f & 15, q = lane >> 4, n = lane & 15;
        int c = ct * 16 + n;
        u32x4_t d;
#pragma unroll
        for (int i = 0; i < 4; ++i) {
            int k = kc * 32 + q * 8 + 2 * i;
            d[i] = pk(W_sw[k * 256 + c], W_sw[(k + 1) * 256 + c]);
        }
        fsp[idx] = d;
    }
}

// ---------------------------------------------------------------------------
// Sites projection via MFMA: xs(bf16)[NS,256] = x_sites @ W_sw, plus fused
// al_s = x_sites @ vs. Wave = 16 sites, 32 MFMAs; LDS-staged coalesced store.
// ---------------------------------------------------------------------------
#define SP_PAD 264   // 256 + 8 ushorts row pad (bank rotation for b16 stores)
__global__ void __launch_bounds__(256)
k_sites_pre(const float* __restrict__ x_sites, const u32x4_t* __restrict__ fsp,
            const float* __restrict__ vs, unsigned short* __restrict__ xs,
            float* __restrict__ al_s)
{
    __shared__ unsigned short stg[4][16 * SP_PAD];
    __shared__ float vsl[256];
    const int tid = threadIdx.x;
    vsl[tid] = vs[tid];
    __syncthreads();
    const int wave = __builtin_amdgcn_readfirstlane(tid >> 6);
    const int lane = tid & 63, q = lane >> 4, n = lane & 15;
    const int sbase = blockIdx.x * 64 + wave * 16;
    const int srow = min(sbase + n, NS_ - 1);
    const float* xr = x_sites + (size_t)srow * 64 + q * 8;
    float4 x0 = *(const float4*)(xr);
    float4 x1 = *(const float4*)(xr + 4);
    float4 x2 = *(const float4*)(xr + 32);
    float4 x3 = *(const float4*)(xr + 36);
    u32x4_t am0 = { pk(x0.x, x0.y), pk(x0.z, x0.w), pk(x1.x, x1.y), pk(x1.z, x1.w) };
    u32x4_t am1 = { pk(x2.x, x2.y), pk(x2.z, x2.w), pk(x3.x, x3.y), pk(x3.z, x3.w) };
    // fused al_s partials over this lane's 16 k-values (fp32 x, exact path)
    float pa[4];
#pragma unroll
    for (int h = 0; h < 4; ++h) {
        const float* v0 = &vsl[(q * 8) * 4 + h];
        const float* v1 = &vsl[(32 + q * 8) * 4 + h];
        pa[h] = x0.x * v0[0]  + x0.y * v0[4]  + x0.z * v0[8]  + x0.w * v0[12]
              + x1.x * v0[16] + x1.y * v0[20] + x1.z * v0[24] + x1.w * v0[28]
              + x2.x * v1[0]  + x2.y * v1[4]  + x2.z * v1[8]  + x2.w * v1[12]
              + x3.x * v1[16] + x3.y * v1[20] + x3.z * v1[24] + x3.w * v1[28];
    }
#pragma unroll
    for (int h = 0; h < 4; ++h) {
        pa[h] += __shfl_xor(pa[h], 16, 64);
        pa[h] += __shfl_xor(pa[h], 32, 64);
    }
    if (q == 0 && sbase + n < NS_)
        *(float4*)(al_s + (size_t)(sbase + n) * 4) = make_float4(pa[0], pa[1], pa[2], pa[3]);

    f32x4_t acc[16];
#pragma unroll
    for (int ct = 0; ct < 16; ++ct) acc[ct] = (f32x4_t){0, 0, 0, 0};
    asm volatile("s_nop 3" : "+v"(am0), "+v"(am1));
#pragma unroll
    for (int ct = 0; ct < 16; ++ct) mfma_bf16(acc[ct], am0, fsp[ct * 64 + lane]);
#pragma unroll
    for (int ct = 0; ct < 16; ++ct) mfma_bf16(acc[ct], am1, fsp[(16 + ct) * 64 + lane]);
    asm volatile("s_nop 7\n\ts_nop 7" ::: "memory");
    // stage to LDS (row = local site, col = channel), then coalesced copy-out
    unsigned short* ss = &stg[wave][0];
#pragma unroll
    for (int ct = 0; ct < 16; ++ct)
#pragma unroll
        for (int reg = 0; reg < 4; ++reg)
            ss[(q * 4 + reg) * SP_PAD + ct * 16 + n] = f2bf(acc[ct][reg]);
    __builtin_amdgcn_s_waitcnt(0);   // drain lgkm before wave-local readback
#pragma unroll
    for (int i = 0; i < 8; ++i) {
        int g = i * 64 + lane;
        int r = g >> 5, c = g & 31;
        if (sbase + r < NS_) {
            u32x4_t v = *(const u32x4_t*)(ss + r * SP_PAD + c * 8);
            *(u32x4_t*)(xs + (size_t)(sbase + r) * 256 + c * 8) = v;
        }
    }
}

// ---------------------------------------------------------------------------
// CSR build: histogram -> 3-phase scan -> scatter (relations merged per launch)
// ---------------------------------------------------------------------------
__global__ void __launch_bounds__(256)
k_hist2(const int* __restrict__ d1, int* __restrict__ h1,
        const int* __restrict__ d2, int* __restrict__ h2)
{
    int e = blockIdx.x * 256 + threadIdx.x;
    if (e >= NE_) return;
    if (blockIdx.y == 0) atomicAdd(&h1[d1[e]], 1);
    else                 atomicAdd(&h2[d2[e]], 1);
}

__global__ void __launch_bounds__(256)
k_scan1_2(const int* __restrict__ h1, int n1, int* __restrict__ b1, int nb1,
          const int* __restrict__ h2, int n2, int* __restrict__ b2)
{
    __shared__ int red[256];
    const int tid = threadIdx.x;
    const int bx = blockIdx.x;
    const int* hist; int n; int* bsum; int blk;
    if (bx < nb1) { hist = h1; n = n1; bsum = b1; blk = bx; }
    else          { hist = h2; n = n2; bsum = b2; blk = bx - nb1; }
    int base = blk * EPB + tid * 8;
    int s = 0;
#pragma unroll
    for (int i = 0; i < 8; ++i) { int idx = base + i; if (idx < n) s += hist[idx]; }
    red[tid] = s;
    __syncthreads();
    for (int off = 128; off > 0; off >>= 1) {
        if (tid < off) red[tid] += red[tid + off];
        __syncthreads();
    }
    if (tid == 0) bsum[blk] = red[0];
}

__global__ void __launch_bounds__(256)
k_scan2_2(int* __restrict__ b1, int nb1, int* __restrict__ b2, int nb2)
{
    __shared__ int sh[256];
    const int tid = threadIdx.x;
    int* bsum = blockIdx.x == 0 ? b1 : b2;
    int nb = blockIdx.x == 0 ? nb1 : nb2;
    sh[tid] = (tid < nb) ? bsum[tid] : 0;
    __syncthreads();
    for (int off = 1; off < 256; off <<= 1) {
        int u = (tid >= off) ? sh[tid - off] : 0;
        __syncthreads();
        sh[tid] += u;
        __syncthreads();
    }
    if (tid < nb) bsum[tid] = (tid == 0) ? 0 : sh[tid - 1];
}

__global__ void __launch_bounds__(256)
k_scan3_2(const int* __restrict__ h1, int n1, const int* __restrict__ b1,
          int* __restrict__ rp1, int* __restrict__ cu1, int nb1,
          const int* __restrict__ h2, int n2, const int* __restrict__ b2,
          int* __restrict__ rp2, int* __restrict__ cu2)
{
    __shared__ int tsum[256];
    const int tid = threadIdx.x;
    const int bx = blockIdx.x;
    const int* hist; int n; const int* bsum; int* rowptr; int* cursor; int blk;
    if (bx < nb1) { hist = h1; n = n1; bsum = b1; rowptr = rp1; cursor = cu1; blk = bx; }
    else          { hist = h2; n = n2; bsum = b2; rowptr = rp2; cursor = cu2; blk = bx - nb1; }
    int base = blk * EPB + tid * 8;
    int v[8]; int s = 0;
#pragma unroll
    for (int i = 0; i < 8; ++i) {
        int idx = base + i;
        v[i] = (idx < n) ? hist[idx] : 0;
        s += v[i];
    }
    tsum[tid] = s;
    __syncthreads();
    for (int off = 1; off < 256; off <<= 1) {
        int u = (tid >= off) ? tsum[tid - off] : 0;
        __syncthreads();
        tsum[tid] += u;
        __syncthreads();
    }
    int texcl = tsum[tid] - s;
    int run = bsum[blk] + texcl;
#pragma unroll
    for (int i = 0; i < 8; ++i) {
        int idx = base + i;
        if (idx < n) { rowptr[idx] = run; cursor[idx] = run; run += v[i]; }
    }
    if (blk == 0 && tid == 0) rowptr[n] = NE_;
}

__global__ void __launch_bounds__(256)
k_scatter2(const int* __restrict__ s1, const int* __restrict__ d1,
           int* __restrict__ c1, int* __restrict__ o1,
           const int* __restrict__ s2, const int* __restrict__ d2,
           int* __restrict__ c2, int* __restrict__ o2)
{
    int e = blockIdx.x * 256 + threadIdx.x;
    if (e >= NE_) return;
    if (blockIdx.y == 0) { int p = atomicAdd(&c1[d1[e]], 1); o1[p] = s1[e]; }
    else                 { int p = atomicAdd(&c2[d2[e]], 1); o2[p] = s2[e]; }
}

// ---------------------------------------------------------------------------
// FUSED wells path: GAT gather + wells dense (MFMA) + output head.
// 16 wells/block, 16 lanes/well for the gather; the block's 4 waves then each
// compute one 16-col tile of t_dense = x_wells@(Wl_ww+Wr_ww) via 2 MFMAs from
// the LDS-staged x rows. Eliminates the tg round-trip AND the x_wells re-read.
// ---------------------------------------------------------------------------
__global__ void __launch_bounds__(256)
k_gat_wells(const float* __restrict__ x_wells, const float* __restrict__ vd,
            const int* __restrict__ rowptr, const int* __restrict__ csr_src,
            const float* __restrict__ al_s, const unsigned short* __restrict__ xs,
            const float* __restrict__ b_sw, const float* __restrict__ bl_ww,
            const u32x4_t* __restrict__ fw, const float* __restrict__ Wg,
            const float* __restrict__ bg, float* __restrict__ out)
{
    __shared__ float vdl[16][17];   // pad 17: conflict-free vdl[p][j] reads
    __shared__ float xw[16][68];    // staged x_wells rows (pad 68, 16B-aligned rows)
    __shared__ float dl[16][68];    // dense MFMA result, [well][channel]
    __shared__ float biasl[64];
    __shared__ float wgl[64];
    __shared__ float res[16];
    const int tid = threadIdx.x;
    vdl[tid >> 4][tid & 15] = vd[tid];
    if (tid < 64) { biasl[tid] = b_sw[tid] + bl_ww[tid]; wgl[tid] = Wg[tid]; }
    __syncthreads();
    const int wl = tid >> 4, p = tid & 15;
    const int w = blockIdx.x * 16 + wl;
    float h0, h1, h2, h3;
    {
        float4 xv = *(const float4*)(x_wells + (size_t)w * 64 + 4 * p);
        *(float4*)&xw[wl][4 * p] = xv;      // stage for the MFMA phase
        const float* vp = vdl[p];
        h0 = xv.x * vp[0] + xv.y * vp[4] + xv.z * vp[8]  + xv.w * vp[12];
        h1 = xv.x * vp[1] + xv.y * vp[5] + xv.z * vp[9]  + xv.w * vp[13];
        h2 = xv.x * vp[2] + xv.y * vp[6] + xv.z * vp[10] + xv.w * vp[14];
        h3 = xv.x * vp[3] + xv.y * vp[7] + xv.z * vp[11] + xv.w * vp[15];
    }
#pragma unroll
    for (int off = 1; off < 16; off <<= 1) {
        h0 += __shfl_xor(h0, off, 64);
        h1 += __shfl_xor(h1, off, 64);
        h2 += __shfl_xor(h2, off, 64);
        h3 += __shfl_xor(h3, off, 64);
    }
    const int r0 = rowptr[w], r1 = rowptr[w + 1];
    float den0 = 0, den1 = 0, den2 = 0, den3 = 0;
    float n0[4] = {0, 0, 0, 0}, n1[4] = {0, 0, 0, 0};
    float n2[4] = {0, 0, 0, 0}, n3[4] = {0, 0, 0, 0};
    for (int j = r0; j < r1; ++j) {
        int s = csr_src[j];
        float4 as = ((const float4*)al_s)[s];
        float e0 = __expf(lrelu02(as.x + h0));
        float e1 = __expf(lrelu02(as.y + h1));
        float e2 = __expf(lrelu02(as.z + h2));
        float e3 = __expf(lrelu02(as.w + h3));
        den0 += e0; den1 += e1; den2 += e2; den3 += e3;
        const unsigned short* xr = xs + (size_t)s * 256 + 4 * p;
        ushort4 u0 = *(const ushort4*)(xr);
        ushort4 u1 = *(const ushort4*)(xr + 64);
        ushort4 u2 = *(const ushort4*)(xr + 128);
        ushort4 u3 = *(const ushort4*)(xr + 192);
        n0[0] += e0 * bf2f(u0.x); n0[1] += e0 * bf2f(u0.y); n0[2] += e0 * bf2f(u0.z); n0[3] += e0 * bf2f(u0.w);
        n1[0] += e1 * bf2f(u1.x); n1[1] += e1 * bf2f(u1.y); n1[2] += e1 * bf2f(u1.z); n1[3] += e1 * bf2f(u1.w);
        n2[0] += e2 * bf2f(u2.x); n2[1] += e2 * bf2f(u2.y); n2[2] += e2 * bf2f(u2.z); n2[3] += e2 * bf2f(u2.w);
        n3[0] += e3 * bf2f(u3.x); n3[1] += e3 * bf2f(u3.y); n3[2] += e3 * bf2f(u3.z); n3[3] += e3 * bf2f(u3.w);
    }
    const int c0 = 4 * p;
    float tmsg[4];
    if (r1 > r0) {
        float i0 = 0.25f / den0, i1 = 0.25f / den1, i2 = 0.25f / den2, i3 = 0.25f / den3;
#pragma unroll
        for (int i = 0; i < 4; ++i)
            tmsg[i] = n0[i] * i0 + n1[i] * i1 + n2[i] * i2 + n3[i] * i3 + biasl[c0 + i];
    } else {
#pragma unroll
        for (int i = 0; i < 4; ++i) tmsg[i] = biasl[c0 + i];
    }
    __syncthreads();   // xw fully staged; safe to read as MFMA fragments
    // ---- dense phase: wave = col-tile ct; A rows = block's 16 wells ----
    const int wave = __builtin_amdgcn_readfirstlane(tid >> 6);
    const int lane = tid & 63, q = lane >> 4, n = lane & 15;
    u32x4_t a0, a1;
#pragma unroll
    for (int i = 0; i < 4; ++i) {
        a0[i] = pk(xw[n][q * 8 + 2 * i],      xw[n][q * 8 + 2 * i + 1]);
        a1[i] = pk(xw[n][32 + q * 8 + 2 * i], xw[n][32 + q * 8 + 2 * i + 1]);
    }
    f32x4_t acc = {0, 0, 0, 0};
    asm volatile("s_nop 3" : "+v"(a0), "+v"(a1), "+v"(acc));
    mfma_bf16(acc, a0, fw[wave * 64 + lane]);
    mfma_bf16(acc, a1, fw[(4 + wave) * 64 + lane]);
    asm volatile("s_nop 7\n\ts_nop 7" : "+v"(acc));
#pragma unroll
    for (int reg = 0; reg < 4; ++reg)
        dl[q * 4 + reg][wave * 16 + n] = acc[reg];   // row=well, col=channel
    __syncthreads();
    float4 dv = *(const float4*)&dl[wl][c0];
    float t0 = tmsg[0] + dv.x;
    float t1 = tmsg[1] + dv.y;
    float t2 = tmsg[2] + dv.z;
    float t3 = tmsg[3] + dv.w;
    float pr = fmaxf(t0, 0.f) * wgl[c0] + fmaxf(t1, 0.f) * wgl[c0 + 1] +
               fmaxf(t2, 0.f) * wgl[c0 + 2] + fmaxf(t3, 0.f) * wgl[c0 + 3];
    pr += __shfl_xor(pr, 1, 64);
    pr += __shfl_xor(pr, 2, 64);
    pr += __shfl_xor(pr, 4, 64);
    pr += __shfl_xor(pr, 8, 64);
    if (p == 0) res[wl] = pr + bg[0];
    __syncthreads();
    if (tid < 16) {
        float v = res[tid];
        out[blockIdx.x * 16 + tid] = v > 0.f ? v : 0.01f * v;
    }
}

// ---------------------------------------------------------------------------
// FUSED sites path: SAGE gather (f32 mean, no bf16 round-trip) + sites dense
// (K=128 MFMA: mn@Wl_ws + x@(Wr_ws+mean W_ss)) + site output head.
// 16 sites/block; waves each compute one 16-col tile (4 MFMAs).
// ---------------------------------------------------------------------------
__global__ void __launch_bounds__(256)
k_sage_sites(const float* __restrict__ x_sites, const float* __restrict__ x_wells,
             const int* __restrict__ rowptr, const int* __restrict__ csr_src,
             const u32x4_t* __restrict__ fs, const float* __restrict__ bl_ws,
             const float* __restrict__ b_ss, const float* __restrict__ Wsit,
             const float* __restrict__ bsit, float* __restrict__ out)
{
    __shared__ float mnL[16][68];
    __shared__ float xL[16][68];
    __shared__ float dl[16][68];
    __shared__ float biasl[64];
    __shared__ float wsl[64];
    __shared__ float res[16];
    const int tid = threadIdx.x;
    if (tid < 64) { biasl[tid] = bl_ws[tid] + b_ss[tid]; wsl[tid] = Wsit[tid]; }
    const int sl = tid >> 4, p = tid & 15;
    const int s = blockIdx.x * 16 + sl;
    const int r0 = rowptr[s], r1 = rowptr[s + 1];
    float4 m4 = {0.f, 0.f, 0.f, 0.f};
    for (int j = r0; j < r1; ++j) {
        int wsrc = csr_src[j];
        float4 xv = ((const float4*)(x_wells + (size_t)wsrc * 64))[p];
        m4.x += xv.x; m4.y += xv.y; m4.z += xv.z; m4.w += xv.w;
    }
    if (r1 > r0) {
        float rc = 1.f / (float)(r1 - r0);
        m4.x *= rc; m4.y *= rc; m4.z *= rc; m4.w *= rc;
    }
    *(float4*)&mnL[sl][4 * p] = m4;
    {
        float4 xv = *(const float4*)(x_sites + (size_t)s * 64 + 4 * p);
        *(float4*)&xL[sl][4 * p] = xv;
    }
    __syncthreads();
    // ---- dense phase: wave = col-tile ct; A rows = block's 16 sites ----
    const int wave = __builtin_amdgcn_readfirstlane(tid >> 6);
    const int lane = tid & 63, q = lane >> 4, n = lane & 15;
    u32x4_t am0, am1, ax0, ax1;
#pragma unroll
    for (int i = 0; i < 4; ++i) {
        am0[i] = pk(mnL[n][q * 8 + 2 * i],      mnL[n][q * 8 + 2 * i + 1]);
        am1[i] = pk(mnL[n][32 + q * 8 + 2 * i], mnL[n][32 + q * 8 + 2 * i + 1]);
        ax0[i] = pk(xL[n][q * 8 + 2 * i],       xL[n][q * 8 + 2 * i + 1]);
        ax1[i] = pk(xL[n][32 + q * 8 + 2 * i],  xL[n][32 + q * 8 + 2 * i + 1]);
    }
    f32x4_t acc = {0, 0, 0, 0};
    asm volatile("s_nop 3" : "+v"(am0), "+v"(am1), "+v"(ax0), "+v"(ax1), "+v"(acc));
    mfma_bf16(acc, am0, fs[wave * 64 + lane]);
    mfma_bf16(acc, am1, fs[(4 + wave) * 64 + lane]);
    mfma_bf16(acc, ax0, fs[(8 + wave) * 64 + lane]);
    mfma_bf16(acc, ax1, fs[(12 + wave) * 64 + lane]);
    asm volatile("s_nop 7\n\ts_nop 7" : "+v"(acc));
#pragma unroll
    for (int reg = 0; reg < 4; ++reg)
        dl[q * 4 + reg][wave * 16 + n] = acc[reg];   // row=site, col=channel
    __syncthreads();
    const int c0 = 4 * p;
    float4 dv = *(const float4*)&dl[sl][c0];
    float t0 = dv.x + biasl[c0];
    float t1 = dv.y + biasl[c0 + 1];
    float t2 = dv.z + biasl[c0 + 2];
    float t3 = dv.w + biasl[c0 + 3];
    float pr = fmaxf(t0, 0.f) * wsl[c0] + fmaxf(t1, 0.f) * wsl[c0 + 1] +
               fmaxf(t2, 0.f) * wsl[c0 + 2] + fmaxf(t3, 0.f) * wsl[c0 + 3];
    pr += __shfl_xor(pr, 1, 64);
    pr += __shfl_xor(pr, 2, 64);
    pr += __shfl_xor(pr, 4, 64);
    pr += __shfl_xor(pr, 8, 64);
    if (p == 0) res[sl] = pr + bsit[0];
    __syncthreads();
    if (tid < 16) {
        float v = res[tid];
        out[(size_t)NW_ + blockIdx.x * 16 + tid] = v > 0.f ? v : 0.01f * v;
    }
}

// ---------------------------------------------------------------------------
extern "C" void kernel_launch(void* const* d_in, const int* in_sizes, int n_in,
                              void* d_out, int out_size, void* d_ws, size_t ws_size,
                              hipStream_t stream)
{
    const float* x_sites    = (const float*)d_in[0];
    const float* x_wells    = (const float*)d_in[1];
    const int*   e_sw_src   = (const int*)d_in[2];
    const int*   e_sw_dst   = (const int*)d_in[3];
    const int*   e_ws_src   = (const int*)d_in[4];
    const int*   e_ws_dst   = (const int*)d_in[5];
    const float* W_sw       = (const float*)d_in[6];
    const float* att_src_sw = (const float*)d_in[7];
    const float* att_dst_sw = (const float*)d_in[8];
    const float* b_sw       = (const float*)d_in[9];
    const float* Wl_ws      = (const float*)d_in[10];
    const float* bl_ws      = (const float*)d_in[11];
    const float* Wr_ws      = (const float*)d_in[12];
    const float* W_ss       = (const float*)d_in[13];
    // d_in[14], d_in[15]: att_*_ss cancel (softmax over single self edge == 1)
    const float* b_ss       = (const float*)d_in[16];
    const float* Wl_ww      = (const float*)d_in[17];
    const float* bl_ww      = (const float*)d_in[18];
    const float* Wr_ww      = (const float*)d_in[19];
    const float* Wg         = (const float*)d_in[20];
    const float* bg         = (const float*)d_in[21];
    const float* Wsit       = (const float*)d_in[22];
    const float* bsit       = (const float*)d_in[23];
    float* out = (float*)d_out;

    // workspace layout (tg/mn intermediates eliminated by fusion)
    unsigned short* xs = (unsigned short*)d_ws;            // NS*256 bf16
    float* al_s = (float*)(xs + (size_t)NS_ * 256);        // NS*4
    float* vd   = al_s + (size_t)NS_ * 4;                  // 256
    float* vs   = vd + 256;                                // 256
    u32x4_t* fw = (u32x4_t*)(vs + 256);                    // 512  (8 KB)
    u32x4_t* fs = fw + 512;                                // 1024 (16 KB)
    u32x4_t* fsp= fs + 1024;                               // 2048 (32 KB)
    int* ip     = (int*)(fsp + 2048);
    int* h_sw   = ip;                                      // NW   (zeroed)
    int* h_ws   = h_sw + NW_;                              // NS   (zeroed, adjacent)
    int* rp_sw  = h_ws + NS_;                              // NW+4
    int* cur_sw = rp_sw + NW_ + 4;                         // NW
    int* csr_sw = cur_sw + NW_;                            // E
    int* bs_sw  = csr_sw + NE_;                            // 256
    int* rp_ws  = bs_sw + 256;                             // NS+4
    int* cur_ws = rp_ws + NS_ + 4;                         // NS
    int* csr_ws = cur_ws + NS_;                            // E
    int* bs_ws  = csr_ws + NE_;                            // 256

    hipMemsetAsync(h_sw, 0, (size_t)(NW_ + NS_) * sizeof(int), stream);

    const int egrid = (NE_ + 255) / 256;
    const int nb_sw = (NW_ + EPB - 1) / EPB;   // 196
    const int nb_ws = (NS_ + EPB - 1) / EPB;   // 49

    hipLaunchKernelGGL(k_hist2, dim3(egrid, 2), dim3(256), 0, stream,
                       e_sw_dst, h_sw, e_ws_dst, h_ws);
    hipLaunchKernelGGL(k_scan1_2, dim3(nb_sw + nb_ws), dim3(256), 0, stream,
                       h_sw, NW_, bs_sw, nb_sw, h_ws, NS_, bs_ws);
    hipLaunchKernelGGL(k_scan2_2, dim3(2), dim3(256), 0, stream,
                       bs_sw, nb_sw, bs_ws, nb_ws);
    hipLaunchKernelGGL(k_scan3_2, dim3(nb_sw + nb_ws), dim3(256), 0, stream,
                       h_sw, NW_, bs_sw, rp_sw, cur_sw, nb_sw,
                       h_ws, NS_, bs_ws, rp_ws, cur_ws);
    hipLaunchKernelGGL(k_scatter2, dim3(egrid, 2), dim3(256), 0, stream,
                       e_sw_src, e_sw_dst, cur_sw, csr_sw,
                       e_ws_src, e_ws_dst, cur_ws, csr_ws);

    hipLaunchKernelGGL(k_prep, dim3(1), dim3(256), 0, stream,
                       W_sw, att_src_sw, att_dst_sw, Wl_ww, Wr_ww, Wl_ws, Wr_ws, W_ss,
                       vd, vs, fw, fs, fsp);
    hipLaunchKernelGGL(k_sites_pre, dim3((NS_ + 63) / 64), dim3(256), 0, stream,
                       x_sites, fsp, vs, xs, al_s);

    hipLaunchKernelGGL(k_gat_wells, dim3(NW_ / 16), dim3(256), 0, stream,
                       x_wells, vd, rp_sw, csr_sw, al_s, xs, b_sw, bl_ww,
                       fw, Wg, bg, out);
    hipLaunchKernelGGL(k_sage_sites, dim3(NS_ / 16), dim3(256), 0, stream,
                       x_sites, x_wells, rp_ws, csr_ws, fs, bl_ws, b_ss,
                       Wsit, bsit, out);
}

// Round 2
// 464.674 us; speedup vs baseline: 1.0603x; 1.0083x over previous
//
#include <hip/hip_runtime.h>

#define NS_ 100000
#define NW_ 400000
#define NE_ 500000
#define EPB 2048   // elements per scan block

typedef float f32x4_t __attribute__((ext_vector_type(4)));
typedef unsigned u32x4_t __attribute__((ext_vector_type(4)));

__device__ __forceinline__ float lrelu02(float x) { return x > 0.f ? x : 0.2f * x; }
__device__ __forceinline__ float bf2f(unsigned short u) {
    return __uint_as_float(((unsigned)u) << 16);
}
__device__ __forceinline__ unsigned short f2bf(float f) {
    unsigned u = __float_as_uint(f);
    u += 0x7FFFu + ((u >> 16) & 1u);           // round-to-nearest-even
    return (unsigned short)(u >> 16);
}
__device__ __forceinline__ unsigned pk(float lo, float hi) {
    return (unsigned)f2bf(lo) | ((unsigned)f2bf(hi) << 16);
}
// D = A*B + D, 16x16x32 bf16. a/b = 8 bf16 packed in 4 dwords (k ascending).
// A[m=lane&15][k=(lane>>4)*8+j]; B[k=(lane>>4)*8+j][n=lane&15];
// D: col=lane&15, row=(lane>>4)*4+reg.   (layout HW-verified in rounds 4/5)
__device__ __forceinline__ void mfma_bf16(f32x4_t& acc, u32x4_t a, u32x4_t b) {
    asm volatile("v_mfma_f32_16x16x32_bf16 %0, %1, %2, %0" : "+v"(acc) : "v"(a), "v"(b));
}

// ---------------------------------------------------------------------------
// Prep (single block): vd/vs attention vectors + all weight B-fragments.
// fw : 8 frags  : Wc = Wl_ww + Wr_ww                  (wells dense, K=64)
// fs : 16 frags : kc0-1 Wl_ws (mn), kc2-3 Wr_ws+mean W_ss (sites dense, K=128)
// fgw: 32 frags : B[h*64+k, c] = W_sw[k, h*64+c]      (agg dense, K=256)
//                 f = kc*4 + ct, kc 0..7, ct 0..3
// ---------------------------------------------------------------------------
__global__ void __launch_bounds__(256)
k_prep(const float* __restrict__ W_sw, const float* __restrict__ att_src,
       const float* __restrict__ att_dst,
       const float* __restrict__ Wl_ww, const float* __restrict__ Wr_ww,
       const float* __restrict__ Wl_ws, const float* __restrict__ Wr_ws,
       const float* __restrict__ W_ss,
       float* __restrict__ vd, float* __restrict__ vs,
       u32x4_t* __restrict__ fw, u32x4_t* __restrict__ fs,
       u32x4_t* __restrict__ fgw)
{
    const int tid = threadIdx.x;
    {   // vd (att_dst) and vs (att_src): v[d*4+h] = sum_c W_sw[d,h*64+c]*att[h,c]
        int d = tid >> 2, h = tid & 3;
        const float4* wp = (const float4*)(W_sw + d * 256 + h * 64);
        const float4* ad = (const float4*)(att_dst + h * 64);
        const float4* as = (const float4*)(att_src + h * 64);
        float accd = 0.f, accs = 0.f;
#pragma unroll
        for (int c = 0; c < 16; ++c) {
            float4 wv = wp[c]; float4 dv = ad[c]; float4 sv = as[c];
            accd += wv.x * dv.x + wv.y * dv.y + wv.z * dv.z + wv.w * dv.w;
            accs += wv.x * sv.x + wv.y * sv.y + wv.z * sv.z + wv.w * sv.w;
        }
        vd[d * 4 + h] = accd;
        vs[d * 4 + h] = accs;
    }
    for (int idx = tid; idx < 512; idx += 256) {
        int f = idx >> 6, lane = idx & 63;
        int kc = f >> 2, ct = f & 3, q = lane >> 4, n = lane & 15;
        int c = ct * 16 + n;
        u32x4_t d;
#pragma unroll
        for (int i = 0; i < 4; ++i) {
            int k = kc * 32 + q * 8 + 2 * i;
            d[i] = pk(Wl_ww[k * 64 + c] + Wr_ww[k * 64 + c],
                      Wl_ww[(k + 1) * 64 + c] + Wr_ww[(k + 1) * 64 + c]);
        }
        fw[idx] = d;
    }
    for (int idx = tid; idx < 1024; idx += 256) {
        int f = idx >> 6, lane = idx & 63;
        int kc = f >> 2, ct = f & 3, q = lane >> 4, n = lane & 15;
        int c = ct * 16 + n;
        u32x4_t d;
#pragma unroll
        for (int i = 0; i < 4; ++i) {
            int k = kc * 32 + q * 8 + 2 * i;
            float lo, hi;
            if (k < 64) {
                lo = Wl_ws[k * 64 + c];
                hi = Wl_ws[(k + 1) * 64 + c];
            } else {
                int kk = k - 64;
                lo = Wr_ws[kk * 64 + c] + 0.25f * (W_ss[kk * 256 + c] + W_ss[kk * 256 + 64 + c] +
                                                   W_ss[kk * 256 + 128 + c] + W_ss[kk * 256 + 192 + c]);
                hi = Wr_ws[(kk + 1) * 64 + c] + 0.25f * (W_ss[(kk + 1) * 256 + c] + W_ss[(kk + 1) * 256 + 64 + c] +
                                                         W_ss[(kk + 1) * 256 + 128 + c] + W_ss[(kk + 1) * 256 + 192 + c]);
            }
            d[i] = pk(lo, hi);
        }
        fs[idx] = d;
    }
    for (int idx = tid; idx < 2048; idx += 256) {
        int f = idx >> 6, lane = idx & 63;
        int kc = f >> 2, ct = f & 3, q = lane >> 4, n = lane & 15;
        int c = ct * 16 + n;
        u32x4_t d;
#pragma unroll
        for (int i = 0; i < 4; ++i) {
            int kk = kc * 32 + q * 8 + 2 * i;      // K index in [0,256): h*64 + k0
            int h = kk >> 6, k0 = kk & 63;         // kk even -> kk+1 same h
            d[i] = pk(W_sw[k0 * 256 + h * 64 + c], W_sw[(k0 + 1) * 256 + h * 64 + c]);
        }
        fgw[idx] = d;
    }
}

// ---------------------------------------------------------------------------
// Sites pre: al_s = x_sites @ vs (exact f32) + bf16 cast xbf of x_sites.
// 64 sites/block, 4 lanes/site (16 ch each). Pure streaming (~40 MB).
// ---------------------------------------------------------------------------
__global__ void __launch_bounds__(256)
k_sites_al(const float* __restrict__ x_sites, const float* __restrict__ vs,
           unsigned short* __restrict__ xbf, float* __restrict__ al_s)
{
    __shared__ float vsl[256];
    const int tid = threadIdx.x;
    vsl[tid] = vs[tid];
    __syncthreads();
    const int s = blockIdx.x * 64 + (tid >> 2);
    const int qq = tid & 3;
    if (s >= NS_) return;   // 4-lane groups exit together (same s)
    const float* xr = x_sites + (size_t)s * 64 + qq * 16;
    float4 a = *(const float4*)(xr);
    float4 b = *(const float4*)(xr + 4);
    float4 c = *(const float4*)(xr + 8);
    float4 d = *(const float4*)(xr + 12);
    float pa[4];
#pragma unroll
    for (int h = 0; h < 4; ++h) {
        const float* v = &vsl[(qq * 16) * 4 + h];
        pa[h] = a.x * v[0]  + a.y * v[4]  + a.z * v[8]  + a.w * v[12]
              + b.x * v[16] + b.y * v[20] + b.z * v[24] + b.w * v[28]
              + c.x * v[32] + c.y * v[36] + c.z * v[40] + c.w * v[44]
              + d.x * v[48] + d.y * v[52] + d.z * v[56] + d.w * v[60];
    }
#pragma unroll
    for (int h = 0; h < 4; ++h) {
        pa[h] += __shfl_xor(pa[h], 1, 64);
        pa[h] += __shfl_xor(pa[h], 2, 64);
    }
    if (qq == 0)
        *(float4*)(al_s + (size_t)s * 4) = make_float4(pa[0], pa[1], pa[2], pa[3]);
    u32x4_t lo = { pk(a.x, a.y), pk(a.z, a.w), pk(b.x, b.y), pk(b.z, b.w) };
    u32x4_t hi = { pk(c.x, c.y), pk(c.z, c.w), pk(d.x, d.y), pk(d.z, d.w) };
    unsigned short* xo = xbf + (size_t)s * 64 + qq * 16;
    *(u32x4_t*)(xo) = lo;
    *(u32x4_t*)(xo + 8) = hi;
}

// ---------------------------------------------------------------------------
// CSR build: histogram -> 3-phase scan -> scatter (relations merged per launch)
// ---------------------------------------------------------------------------
__global__ void __launch_bounds__(256)
k_hist2(const int* __restrict__ d1, int* __restrict__ h1,
        const int* __restrict__ d2, int* __restrict__ h2)
{
    int e = blockIdx.x * 256 + threadIdx.x;
    if (e >= NE_) return;
    if (blockIdx.y == 0) atomicAdd(&h1[d1[e]], 1);
    else                 atomicAdd(&h2[d2[e]], 1);
}

__global__ void __launch_bounds__(256)
k_scan1_2(const int* __restrict__ h1, int n1, int* __restrict__ b1, int nb1,
          const int* __restrict__ h2, int n2, int* __restrict__ b2)
{
    __shared__ int red[256];
    const int tid = threadIdx.x;
    const int bx = blockIdx.x;
    const int* hist; int n; int* bsum; int blk;
    if (bx < nb1) { hist = h1; n = n1; bsum = b1; blk = bx; }
    else          { hist = h2; n = n2; bsum = b2; blk = bx - nb1; }
    int base = blk * EPB + tid * 8;
    int s = 0;
#pragma unroll
    for (int i = 0; i < 8; ++i) { int idx = base + i; if (idx < n) s += hist[idx]; }
    red[tid] = s;
    __syncthreads();
    for (int off = 128; off > 0; off >>= 1) {
        if (tid < off) red[tid] += red[tid + off];
        __syncthreads();
    }
    if (tid == 0) bsum[blk] = red[0];
}

__global__ void __launch_bounds__(256)
k_scan2_2(int* __restrict__ b1, int nb1, int* __restrict__ b2, int nb2)
{
    __shared__ int sh[256];
    const int tid = threadIdx.x;
    int* bsum = blockIdx.x == 0 ? b1 : b2;
    int nb = blockIdx.x == 0 ? nb1 : nb2;
    sh[tid] = (tid < nb) ? bsum[tid] : 0;
    __syncthreads();
    for (int off = 1; off < 256; off <<= 1) {
        int u = (tid >= off) ? sh[tid - off] : 0;
        __syncthreads();
        sh[tid] += u;
        __syncthreads();
    }
    if (tid < nb) bsum[tid] = (tid == 0) ? 0 : sh[tid - 1];
}

__global__ void __launch_bounds__(256)
k_scan3_2(const int* __restrict__ h1, int n1, const int* __restrict__ b1,
          int* __restrict__ rp1, int* __restrict__ cu1, int nb1,
          const int* __restrict__ h2, int n2, const int* __restrict__ b2,
          int* __restrict__ rp2, int* __restrict__ cu2)
{
    __shared__ int tsum[256];
    const int tid = threadIdx.x;
    const int bx = blockIdx.x;
    const int* hist; int n; const int* bsum; int* rowptr; int* cursor; int blk;
    if (bx < nb1) { hist = h1; n = n1; bsum = b1; rowptr = rp1; cursor = cu1; blk = bx; }
    else          { hist = h2; n = n2; bsum = b2; rowptr = rp2; cursor = cu2; blk = bx - nb1; }
    int base = blk * EPB + tid * 8;
    int v[8]; int s = 0;
#pragma unroll
    for (int i = 0; i < 8; ++i) {
        int idx = base + i;
        v[i] = (idx < n) ? hist[idx] : 0;
        s += v[i];
    }
    tsum[tid] = s;
    __syncthreads();
    for (int off = 1; off < 256; off <<= 1) {
        int u = (tid >= off) ? tsum[tid - off] : 0;
        __syncthreads();
        tsum[tid] += u;
        __syncthreads();
    }
    int texcl = tsum[tid] - s;
    int run = bsum[blk] + texcl;
#pragma unroll
    for (int i = 0; i < 8; ++i) {
        int idx = base + i;
        if (idx < n) { rowptr[idx] = run; cursor[idx] = run; run += v[i]; }
    }
    if (blk == 0 && tid == 0) rowptr[n] = NE_;
}

__global__ void __launch_bounds__(256)
k_scatter2(const int* __restrict__ s1, const int* __restrict__ d1,
           int* __restrict__ c1, int* __restrict__ o1,
           const int* __restrict__ s2, const int* __restrict__ d2,
           int* __restrict__ c2, int* __restrict__ o2)
{
    int e = blockIdx.x * 256 + threadIdx.x;
    if (e >= NE_) return;
    if (blockIdx.y == 0) { int p = atomicAdd(&c1[d1[e]], 1); o1[p] = s1[e]; }
    else                 { int p = atomicAdd(&c2[d2[e]], 1); o2[p] = s2[e]; }
}

// ---------------------------------------------------------------------------
// FUSED wells path: GAT gather on RAW x_sites (per-head weighted sums, f32),
// then K=256 MFMA applies W_sw, + K=64 x_wells dense, + output head.
// msg linearity: sum_s a^h_s (x_s@W)[h64+c] = (sum_s a^h_s x_s) @ W[:,h64+c].
// Per edge: 16 B al_s + 128 B xbf (vs 528 B before). 16 wells/block.
// ---------------------------------------------------------------------------
__global__ void __launch_bounds__(256)
k_gat_wells(const float* __restrict__ x_wells, const float* __restrict__ vd,
            const int* __restrict__ rowptr, const int* __restrict__ csr_src,
            const float* __restrict__ al_s, const unsigned short* __restrict__ xbf,
            const float* __restrict__ b_sw, const float* __restrict__ bl_ww,
            const u32x4_t* __restrict__ fw, const u32x4_t* __restrict__ fgw,
            const float* __restrict__ Wg, const float* __restrict__ bg,
            float* __restrict__ out)
{
    __shared__ float vdl[16][17];     // pad 17: conflict-free vdl[p][j] reads
    __shared__ unsigned xwB[16][36];  // x_wells rows, bf16 pairs (K=64)
    __shared__ unsigned agB[16][132]; // normalized agg, bf16 pairs (K=256)
    __shared__ float dl[16][68];      // MFMA result, [well][channel]
    __shared__ float biasl[64];
    __shared__ float wgl[64];
    __shared__ float res[16];
    const int tid = threadIdx.x;
    vdl[tid >> 4][tid & 15] = vd[tid];
    if (tid < 64) { biasl[tid] = b_sw[tid] + bl_ww[tid]; wgl[tid] = Wg[tid]; }
    __syncthreads();
    const int wl = tid >> 4, p = tid & 15;
    const int w = blockIdx.x * 16 + wl;
    float h0, h1, h2, h3;
    {
        float4 xv = *(const float4*)(x_wells + (size_t)w * 64 + 4 * p);
        *(uint2*)&xwB[wl][2 * p] = make_uint2(pk(xv.x, xv.y), pk(xv.z, xv.w));
        const float* vp = vdl[p];
        h0 = xv.x * vp[0] + xv.y * vp[4] + xv.z * vp[8]  + xv.w * vp[12];
        h1 = xv.x * vp[1] + xv.y * vp[5] + xv.z * vp[9]  + xv.w * vp[13];
        h2 = xv.x * vp[2] + xv.y * vp[6] + xv.z * vp[10] + xv.w * vp[14];
        h3 = xv.x * vp[3] + xv.y * vp[7] + xv.z * vp[11] + xv.w * vp[15];
    }
#pragma unroll
    for (int off = 1; off < 16; off <<= 1) {
        h0 += __shfl_xor(h0, off, 64);
        h1 += __shfl_xor(h1, off, 64);
        h2 += __shfl_xor(h2, off, 64);
        h3 += __shfl_xor(h3, off, 64);
    }
    const int r0 = rowptr[w], r1 = rowptr[w + 1];
    float den0 = 0, den1 = 0, den2 = 0, den3 = 0;
    // per-head weighted sums of raw x_sites channels 4p..4p+3
    float a00=0,a01=0,a02=0,a03=0, a10=0,a11=0,a12=0,a13=0;
    float a20=0,a21=0,a22=0,a23=0, a30=0,a31=0,a32=0,a33=0;
    for (int j = r0; j < r1; ++j) {
        int s = csr_src[j];
        float4 as = ((const float4*)al_s)[s];
        ushort4 u = *(const ushort4*)(xbf + (size_t)s * 64 + 4 * p);
        float e0 = __expf(lrelu02(as.x + h0));
        float e1 = __expf(lrelu02(as.y + h1));
        float e2 = __expf(lrelu02(as.z + h2));
        float e3 = __expf(lrelu02(as.w + h3));
        den0 += e0; den1 += e1; den2 += e2; den3 += e3;
        float x0 = bf2f(u.x), x1 = bf2f(u.y), x2 = bf2f(u.z), x3 = bf2f(u.w);
        a00 += e0 * x0; a01 += e0 * x1; a02 += e0 * x2; a03 += e0 * x3;
        a10 += e1 * x0; a11 += e1 * x1; a12 += e1 * x2; a13 += e1 * x3;
        a20 += e2 * x0; a21 += e2 * x1; a22 += e2 * x2; a23 += e2 * x3;
        a30 += e3 * x0; a31 += e3 * x1; a32 += e3 * x2; a33 += e3 * x3;
    }
    if (r1 > r0) {   // fold 1/4 head-mean into the normalize
        float i0 = 0.25f / den0, i1 = 0.25f / den1, i2 = 0.25f / den2, i3 = 0.25f / den3;
        a00 *= i0; a01 *= i0; a02 *= i0; a03 *= i0;
        a10 *= i1; a11 *= i1; a12 *= i1; a13 *= i1;
        a20 *= i2; a21 *= i2; a22 *= i2; a23 *= i2;
        a30 *= i3; a31 *= i3; a32 *= i3; a33 *= i3;
    }
    // stage agg as bf16 pairs: K-index kk = h*64 + 4p + j -> dword kk/2
    *(uint2*)&agB[wl][0 * 32 + 2 * p] = make_uint2(pk(a00, a01), pk(a02, a03));
    *(uint2*)&agB[wl][1 * 32 + 2 * p] = make_uint2(pk(a10, a11), pk(a12, a13));
    *(uint2*)&agB[wl][2 * 32 + 2 * p] = make_uint2(pk(a20, a21), pk(a22, a23));
    *(uint2*)&agB[wl][3 * 32 + 2 * p] = make_uint2(pk(a30, a31), pk(a32, a33));
    __syncthreads();
    // ---- dense phase: wave = col-tile ct; A rows = block's 16 wells ----
    const int wave = __builtin_amdgcn_readfirstlane(tid >> 6);
    const int lane = tid & 63, q = lane >> 4, n = lane & 15;
    u32x4_t ax0 = *(const u32x4_t*)&xwB[n][q * 4];
    u32x4_t ax1 = *(const u32x4_t*)&xwB[n][16 + q * 4];
    f32x4_t acc = {0, 0, 0, 0};
    asm volatile("s_nop 3" : "+v"(ax0), "+v"(ax1), "+v"(acc));
    mfma_bf16(acc, ax0, fw[wave * 64 + lane]);
    mfma_bf16(acc, ax1, fw[(4 + wave) * 64 + lane]);
#pragma unroll
    for (int kc = 0; kc < 8; ++kc) {
        u32x4_t a = *(const u32x4_t*)&agB[n][kc * 16 + q * 4];
        mfma_bf16(acc, a, fgw[(kc * 4 + wave) * 64 + lane]);
    }
    asm volatile("s_nop 7\n\ts_nop 7" : "+v"(acc));
#pragma unroll
    for (int reg = 0; reg < 4; ++reg)
        dl[q * 4 + reg][wave * 16 + n] = acc[reg];   // row=well, col=channel
    __syncthreads();
    const int c0 = 4 * p;
    float4 dv = *(const float4*)&dl[wl][c0];
    float t0 = dv.x + biasl[c0];
    float t1 = dv.y + biasl[c0 + 1];
    float t2 = dv.z + biasl[c0 + 2];
    float t3 = dv.w + biasl[c0 + 3];
    float pr = fmaxf(t0, 0.f) * wgl[c0] + fmaxf(t1, 0.f) * wgl[c0 + 1] +
               fmaxf(t2, 0.f) * wgl[c0 + 2] + fmaxf(t3, 0.f) * wgl[c0 + 3];
    pr += __shfl_xor(pr, 1, 64);
    pr += __shfl_xor(pr, 2, 64);
    pr += __shfl_xor(pr, 4, 64);
    pr += __shfl_xor(pr, 8, 64);
    if (p == 0) res[wl] = pr + bg[0];
    __syncthreads();
    if (tid < 16) {
        float v = res[tid];
        out[blockIdx.x * 16 + tid] = v > 0.f ? v : 0.01f * v;
    }
}

// ---------------------------------------------------------------------------
// FUSED sites path: SAGE gather (f32 mean) + sites dense (K=128 MFMA) + head.
// A-operands staged as bf16 pairs in LDS (no repack in MFMA phase).
// ---------------------------------------------------------------------------
__global__ void __launch_bounds__(256)
k_sage_sites(const float* __restrict__ x_sites, const float* __restrict__ x_wells,
             const int* __restrict__ rowptr, const int* __restrict__ csr_src,
             const u32x4_t* __restrict__ fs, const float* __restrict__ bl_ws,
             const float* __restrict__ b_ss, const float* __restrict__ Wsit,
             const float* __restrict__ bsit, float* __restrict__ out)
{
    __shared__ unsigned mnB[16][36];
    __shared__ unsigned xB[16][36];
    __shared__ float dl[16][68];
    __shared__ float biasl[64];
    __shared__ float wsl[64];
    __shared__ float res[16];
    const int tid = threadIdx.x;
    if (tid < 64) { biasl[tid] = bl_ws[tid] + b_ss[tid]; wsl[tid] = Wsit[tid]; }
    const int sl = tid >> 4, p = tid & 15;
    const int s = blockIdx.x * 16 + sl;
    const int r0 = rowptr[s], r1 = rowptr[s + 1];
    float4 m4 = {0.f, 0.f, 0.f, 0.f};
    for (int j = r0; j < r1; ++j) {
        int wsrc = csr_src[j];
        float4 xv = ((const float4*)(x_wells + (size_t)wsrc * 64))[p];
        m4.x += xv.x; m4.y += xv.y; m4.z += xv.z; m4.w += xv.w;
    }
    if (r1 > r0) {
        float rc = 1.f / (float)(r1 - r0);
        m4.x *= rc; m4.y *= rc; m4.z *= rc; m4.w *= rc;
    }
    *(uint2*)&mnB[sl][2 * p] = make_uint2(pk(m4.x, m4.y), pk(m4.z, m4.w));
    {
        float4 xv = *(const float4*)(x_sites + (size_t)s * 64 + 4 * p);
        *(uint2*)&xB[sl][2 * p] = make_uint2(pk(xv.x, xv.y), pk(xv.z, xv.w));
    }
    __syncthreads();
    // ---- dense phase: wave = col-tile ct; A rows = block's 16 sites ----
    const int wave = __builtin_amdgcn_readfirstlane(tid >> 6);
    const int lane = tid & 63, q = lane >> 4, n = lane & 15;
    u32x4_t am0 = *(const u32x4_t*)&mnB[n][q * 4];
    u32x4_t am1 = *(const u32x4_t*)&mnB[n][16 + q * 4];
    u32x4_t ax0 = *(const u32x4_t*)&xB[n][q * 4];
    u32x4_t ax1 = *(const u32x4_t*)&xB[n][16 + q * 4];
    f32x4_t acc = {0, 0, 0, 0};
    asm volatile("s_nop 3" : "+v"(am0), "+v"(am1), "+v"(ax0), "+v"(ax1), "+v"(acc));
    mfma_bf16(acc, am0, fs[wave * 64 + lane]);
    mfma_bf16(acc, am1, fs[(4 + wave) * 64 + lane]);
    mfma_bf16(acc, ax0, fs[(8 + wave) * 64 + lane]);
    mfma_bf16(acc, ax1, fs[(12 + wave) * 64 + lane]);
    asm volatile("s_nop 7\n\ts_nop 7" : "+v"(acc));
#pragma unroll
    for (int reg = 0; reg < 4; ++reg)
        dl[q * 4 + reg][wave * 16 + n] = acc[reg];   // row=site, col=channel
    __syncthreads();
    const int c0 = 4 * p;
    float4 dv = *(const float4*)&dl[sl][c0];
    float t0 = dv.x + biasl[c0];
    float t1 = dv.y + biasl[c0 + 1];
    float t2 = dv.z + biasl[c0 + 2];
    float t3 = dv.w + biasl[c0 + 3];
    float pr = fmaxf(t0, 0.f) * wsl[c0] + fmaxf(t1, 0.f) * wsl[c0 + 1] +
               fmaxf(t2, 0.f) * wsl[c0 + 2] + fmaxf(t3, 0.f) * wsl[c0 + 3];
    pr += __shfl_xor(pr, 1, 64);
    pr += __shfl_xor(pr, 2, 64);
    pr += __shfl_xor(pr, 4, 64);
    pr += __shfl_xor(pr, 8, 64);
    if (p == 0) res[sl] = pr + bsit[0];
    __syncthreads();
    if (tid < 16) {
        float v = res[tid];
        out[(size_t)NW_ + blockIdx.x * 16 + tid] = v > 0.f ? v : 0.01f * v;
    }
}

// ---------------------------------------------------------------------------
extern "C" void kernel_launch(void* const* d_in, const int* in_sizes, int n_in,
                              void* d_out, int out_size, void* d_ws, size_t ws_size,
                              hipStream_t stream)
{
    const float* x_sites    = (const float*)d_in[0];
    const float* x_wells    = (const float*)d_in[1];
    const int*   e_sw_src   = (const int*)d_in[2];
    const int*   e_sw_dst   = (const int*)d_in[3];
    const int*   e_ws_src   = (const int*)d_in[4];
    const int*   e_ws_dst   = (const int*)d_in[5];
    const float* W_sw       = (const float*)d_in[6];
    const float* att_src_sw = (const float*)d_in[7];
    const float* att_dst_sw = (const float*)d_in[8];
    const float* b_sw       = (const float*)d_in[9];
    const float* Wl_ws      = (const float*)d_in[10];
    const float* bl_ws      = (const float*)d_in[11];
    const float* Wr_ws      = (const float*)d_in[12];
    const float* W_ss       = (const float*)d_in[13];
    // d_in[14], d_in[15]: att_*_ss cancel (softmax over single self edge == 1)
    const float* b_ss       = (const float*)d_in[16];
    const float* Wl_ww      = (const float*)d_in[17];
    const float* bl_ww      = (const float*)d_in[18];
    const float* Wr_ww      = (const float*)d_in[19];
    const float* Wg         = (const float*)d_in[20];
    const float* bg         = (const float*)d_in[21];
    const float* Wsit       = (const float*)d_in[22];
    const float* bsit       = (const float*)d_in[23];
    float* out = (float*)d_out;

    // workspace layout (xs projection eliminated; xbf = bf16 x_sites copy)
    unsigned short* xbf = (unsigned short*)d_ws;           // NS*64 bf16
    float* al_s = (float*)(xbf + (size_t)NS_ * 64);        // NS*4
    float* vd   = al_s + (size_t)NS_ * 4;                  // 256
    float* vs   = vd + 256;                                // 256
    u32x4_t* fw = (u32x4_t*)(vs + 256);                    // 512  (8 KB)
    u32x4_t* fs = fw + 512;                                // 1024 (16 KB)
    u32x4_t* fgw= fs + 1024;                               // 2048 (32 KB)
    int* ip     = (int*)(fgw + 2048);
    int* h_sw   = ip;                                      // NW   (zeroed)
    int* h_ws   = h_sw + NW_;                              // NS   (zeroed, adjacent)
    int* rp_sw  = h_ws + NS_;                              // NW+4
    int* cur_sw = rp_sw + NW_ + 4;                         // NW
    int* csr_sw = cur_sw + NW_;                            // E
    int* bs_sw  = csr_sw + NE_;                            // 256
    int* rp_ws  = bs_sw + 256;                             // NS+4
    int* cur_ws = rp_ws + NS_ + 4;                         // NS
    int* csr_ws = cur_ws + NS_;                            // E
    int* bs_ws  = csr_ws + NE_;                            // 256

    hipMemsetAsync(h_sw, 0, (size_t)(NW_ + NS_) * sizeof(int), stream);

    const int egrid = (NE_ + 255) / 256;
    const int nb_sw = (NW_ + EPB - 1) / EPB;   // 196
    const int nb_ws = (NS_ + EPB - 1) / EPB;   // 49

    hipLaunchKernelGGL(k_hist2, dim3(egrid, 2), dim3(256), 0, stream,
                       e_sw_dst, h_sw, e_ws_dst, h_ws);
    hipLaunchKernelGGL(k_scan1_2, dim3(nb_sw + nb_ws), dim3(256), 0, stream,
                       h_sw, NW_, bs_sw, nb_sw, h_ws, NS_, bs_ws);
    hipLaunchKernelGGL(k_scan2_2, dim3(2), dim3(256), 0, stream,
                       bs_sw, nb_sw, bs_ws, nb_ws);
    hipLaunchKernelGGL(k_scan3_2, dim3(nb_sw + nb_ws), dim3(256), 0, stream,
                       h_sw, NW_, bs_sw, rp_sw, cur_sw, nb_sw,
                       h_ws, NS_, bs_ws, rp_ws, cur_ws);
    hipLaunchKernelGGL(k_scatter2, dim3(egrid, 2), dim3(256), 0, stream,
                       e_sw_src, e_sw_dst, cur_sw, csr_sw,
                       e_ws_src, e_ws_dst, cur_ws, csr_ws);

    hipLaunchKernelGGL(k_prep, dim3(1), dim3(256), 0, stream,
                       W_sw, att_src_sw, att_dst_sw, Wl_ww, Wr_ww, Wl_ws, Wr_ws, W_ss,
                       vd, vs, fw, fs, fgw);
    hipLaunchKernelGGL(k_sites_al, dim3((NS_ + 63) / 64), dim3(256), 0, stream,
                       x_sites, vs, xbf, al_s);

    hipLaunchKernelGGL(k_gat_wells, dim3(NW_ / 16), dim3(256), 0, stream,
                       x_wells, vd, rp_sw, csr_sw, al_s, xbf, b_sw, bl_ww,
                       fw, fgw, Wg, bg, out);
    hipLaunchKernelGGL(k_sage_sites, dim3(NS_ / 16), dim3(256), 0, stream,
                       x_sites, x_wells, rp_ws, csr_ws, fs, bl_ws, b_ss,
                       Wsit, bsit, out);
}